// Round 1
// baseline (86.103 us; speedup 1.0000x reference)
//
#include <hip/hip_runtime.h>

// PointPairwiseRelation3: decomposed pairwise MLP.
// h_pre[b,n,j,k,:] = base[b,n,:] + p[b,j,:] + q[b,k,:]
//   base = x@(Wa-Wb-Wc)+b1, p = x1@Wb, q = x2@Wc
// out2 = relu(relu(h_pre) @ W2 + b2); max over cols 0-7, mean over cols 8-15.
// One block per (b,n); MFMA 16x16x16 f16 for the second layer.

typedef _Float16 f16x2 __attribute__((ext_vector_type(2)));
typedef _Float16 f16x4 __attribute__((ext_vector_type(4)));
typedef float f32x4 __attribute__((ext_vector_type(4)));

__global__ __launch_bounds__(512, 4) void ppr_kernel(
    const float* __restrict__ x, const float* __restrict__ x1,
    const float* __restrict__ x2, const float* __restrict__ W1,
    const float* __restrict__ b1, const float* __restrict__ W2,
    const float* __restrict__ b2, float* __restrict__ out)
{
    // rows padded to 20 halfs (40B) -> ds_read_b64 across 16 lanes is ~2-way, free
    __shared__ _Float16 p_lds[128][20];
    __shared__ _Float16 q_lds[128][20];
    __shared__ __align__(8) _Float16 base_lds[16];
    __shared__ float red_m[8][64];
    __shared__ float red_s[8][64];

    const int tid = threadIdx.x;
    const int blk = blockIdx.x;
    const int b = blk >> 8;     // batch
    const int n = blk & 255;    // query point

    // ---------------- prologue: p, q, base into LDS ----------------
    if (tid < 256) {
        const bool isP = (tid < 128);
        const int row = tid & 127;
        const float* src = isP ? (x1 + (b * 128 + row) * 16)
                               : (x2 + (b * 128 + row) * 16);
        const float* W = W1 + (isP ? 16 : 32) * 16;  // Wb or Wc, row-major (16,16)
        float xv[16];
        const float4* s4 = (const float4*)src;
        #pragma unroll
        for (int i = 0; i < 4; ++i) {
            float4 v = s4[i];
            xv[4*i+0] = v.x; xv[4*i+1] = v.y; xv[4*i+2] = v.z; xv[4*i+3] = v.w;
        }
        float r[16];
        #pragma unroll
        for (int c = 0; c < 16; ++c) r[c] = 0.f;
        #pragma unroll
        for (int i = 0; i < 16; ++i) {
            const float xi = xv[i];
            #pragma unroll
            for (int c = 0; c < 16; ++c)
                r[c] = fmaf(xi, W[i * 16 + c], r[c]);
        }
        _Float16* dst = isP ? &p_lds[row][0] : &q_lds[row][0];
        #pragma unroll
        for (int c = 0; c < 16; c += 4) {
            f16x4 v = { (_Float16)r[c], (_Float16)r[c+1],
                        (_Float16)r[c+2], (_Float16)r[c+3] };
            *(f16x4*)(dst + c) = v;
        }
    }
    if (tid < 16) {
        const int c = tid;
        const float* xn = x + (b * 256 + n) * 16;
        float acc = b1[c];
        #pragma unroll
        for (int i = 0; i < 16; ++i) {
            const float w = W1[i * 16 + c] - W1[(16 + i) * 16 + c]
                          - W1[(32 + i) * 16 + c];
            acc = fmaf(xn[i], w, acc);
        }
        base_lds[c] = (_Float16)acc;
    }

    // ---------------- per-lane MFMA fragments ----------------
    const int lane = tid & 63;
    const int wave = tid >> 6;
    const int col  = lane & 15;   // output channel (B/D col)
    const int quad = lane >> 4;
    const int c0   = quad * 4;    // K (=hidden channel) base for A/B frags
    const int m    = lane & 15;   // A row within tile = k-offset inside k-tile

    f16x4 bfrag;                  // B[k=c0+i][n=col] = W2[c0+i][col]
    #pragma unroll
    for (int i = 0; i < 4; ++i) bfrag[i] = (_Float16)W2[(c0 + i) * 16 + col];
    const float b2c = b2[col];
    const f32x4 cb2 = { b2c, b2c, b2c, b2c };

    __syncthreads();

    const f16x4 base4 = *(const f16x4*)&base_lds[c0];
    const f16x4 zero4 = { (_Float16)0, (_Float16)0, (_Float16)0, (_Float16)0 };

    f32x4 am = {0.f, 0.f, 0.f, 0.f};  // running max  (relu folded: init 0)
    f32x4 as = {0.f, 0.f, 0.f, 0.f};  // running sum of relu

    // wave w owns j in [w*16, w*16+16); 8 k-tiles of 16 each -> 128 MFMAs/wave
    #pragma unroll 1
    for (int j = wave * 16; j < wave * 16 + 16; ++j) {
        const f16x4 p4 = *(const f16x4*)&p_lds[j][c0] + base4;
        #pragma unroll
        for (int kt = 0; kt < 8; ++kt) {
            const int k = kt * 16 + m;
            const f16x4 q4 = *(const f16x4*)&q_lds[k][c0];
            const f16x4 af = __builtin_elementwise_max(p4 + q4, zero4);
            const f32x4 d = __builtin_amdgcn_mfma_f32_16x16x16f16(af, bfrag, cb2, 0, 0, 0);
            #pragma unroll
            for (int r2 = 0; r2 < 4; ++r2) {
                am[r2] = fmaxf(am[r2], d[r2]);
                as[r2] += fmaxf(d[r2], 0.f);
            }
        }
    }

    red_m[wave][lane] = fmaxf(fmaxf(am[0], am[1]), fmaxf(am[2], am[3]));
    red_s[wave][lane] = as[0] + as[1] + as[2] + as[3];
    __syncthreads();

    // ---------------- epilogue: cross-wave reduce, write out ----------------
    if (tid < 16) {
        float mm = 0.f, ss = 0.f;
        #pragma unroll
        for (int w = 0; w < 8; ++w) {
            #pragma unroll
            for (int qd = 0; qd < 4; ++qd) {
                mm = fmaxf(mm, red_m[w][qd * 16 + tid]);
                ss += red_s[w][qd * 16 + tid];
            }
        }
        out[(b * 256 + n) * 16 + tid] = (tid < 8) ? mm : ss * (1.0f / 16384.0f);
    }
}

extern "C" void kernel_launch(void* const* d_in, const int* in_sizes, int n_in,
                              void* d_out, int out_size, void* d_ws, size_t ws_size,
                              hipStream_t stream) {
    const float* x  = (const float*)d_in[0];
    const float* x1 = (const float*)d_in[1];
    const float* x2 = (const float*)d_in[2];
    const float* W1 = (const float*)d_in[3];
    const float* b1 = (const float*)d_in[4];
    const float* W2 = (const float*)d_in[5];
    const float* b2 = (const float*)d_in[6];
    float* out = (float*)d_out;
    ppr_kernel<<<dim3(512), dim3(512), 0, stream>>>(x, x1, x2, W1, b1, W2, b2, out);
}

// Round 2
// 85.218 us; speedup vs baseline: 1.0104x; 1.0104x over previous
//
#include <hip/hip_runtime.h>

// PointPairwiseRelation3: decomposed pairwise MLP.
// h_pre[b,n,j,k,:] = base[b,n,:] + p[b,j,:] + q[b,k,:]
//   base = x@(Wa-Wb-Wc)+b1, p = x1@Wb, q = x2@Wc
// out2 = relu(relu(h_pre) @ W2 + b2); max over cols 0-7, mean over cols 8-15.
// One block per (b,n); MFMA 16x16x16 f16 for the second layer.
// VALU-issue-bound: q-tiles register-cached, max3-fused reduce, pk_add_f32 sums.

typedef _Float16 f16x4 __attribute__((ext_vector_type(4)));
typedef float f32x4 __attribute__((ext_vector_type(4)));

__global__ __launch_bounds__(512, 4) void ppr_kernel(
    const float* __restrict__ x, const float* __restrict__ x1,
    const float* __restrict__ x2, const float* __restrict__ W1,
    const float* __restrict__ b1, const float* __restrict__ W2,
    const float* __restrict__ b2, float* __restrict__ out)
{
    // rows padded to 20 halfs (40B): quad-pair b64 reads spread over all 32 banks
    __shared__ _Float16 p_lds[128][20];
    __shared__ _Float16 q_lds[128][20];
    __shared__ __align__(8) _Float16 base_lds[16];
    __shared__ float red_m[8][64];
    __shared__ float red_s[8][64];

    const int tid = threadIdx.x;
    const int blk = blockIdx.x;
    const int b = blk >> 8;     // batch
    const int n = blk & 255;    // query point

    // ---------------- prologue: p, q (all 512 threads), base into LDS ----------------
    {
        const int task = tid >> 1;          // 0..255: which row of which matrix
        const int half = tid & 1;           // channel half: 8 channels each
        const bool isP = (task < 128);
        const int row = task & 127;
        const float* src = isP ? (x1 + (b * 128 + row) * 16)
                               : (x2 + (b * 128 + row) * 16);
        const float* W = W1 + (isP ? 16 : 32) * 16 + half * 8;  // Wb/Wc cols half*8..
        float xv[16];
        const float4* s4 = (const float4*)src;
        #pragma unroll
        for (int i = 0; i < 4; ++i) {
            float4 v = s4[i];
            xv[4*i+0] = v.x; xv[4*i+1] = v.y; xv[4*i+2] = v.z; xv[4*i+3] = v.w;
        }
        float r[8];
        #pragma unroll
        for (int c = 0; c < 8; ++c) r[c] = 0.f;
        #pragma unroll
        for (int i = 0; i < 16; ++i) {
            const float xi = xv[i];
            #pragma unroll
            for (int c = 0; c < 8; ++c)
                r[c] = fmaf(xi, W[i * 16 + c], r[c]);
        }
        _Float16* dst = (isP ? &p_lds[row][0] : &q_lds[row][0]) + half * 8;
        #pragma unroll
        for (int c = 0; c < 8; c += 4) {
            f16x4 v = { (_Float16)r[c], (_Float16)r[c+1],
                        (_Float16)r[c+2], (_Float16)r[c+3] };
            *(f16x4*)(dst + c) = v;
        }
    }
    if (tid < 16) {
        const int c = tid;
        const float* xn = x + (b * 256 + n) * 16;
        float acc = b1[c];
        #pragma unroll
        for (int i = 0; i < 16; ++i) {
            const float w = W1[i * 16 + c] - W1[(16 + i) * 16 + c]
                          - W1[(32 + i) * 16 + c];
            acc = fmaf(xn[i], w, acc);
        }
        base_lds[c] = (_Float16)acc;
    }

    // ---------------- per-lane MFMA fragments ----------------
    const int lane = tid & 63;
    const int wave = tid >> 6;
    const int col  = lane & 15;   // output channel (B/D col)
    const int quad = lane >> 4;
    const int c0   = quad * 4;    // K (=hidden channel) base for A/B frags
    const int m    = lane & 15;   // A row within tile = k-offset inside k-tile

    f16x4 bfrag;                  // B[k=c0+i][n=col] = W2[c0+i][col]
    #pragma unroll
    for (int i = 0; i < 4; ++i) bfrag[i] = (_Float16)W2[(c0 + i) * 16 + col];
    const float b2c = b2[col];
    const f32x4 cb2 = { b2c, b2c, b2c, b2c };

    __syncthreads();

    const f16x4 base4 = *(const f16x4*)&base_lds[c0];
    const f16x4 zero4 = { (_Float16)0, (_Float16)0, (_Float16)0, (_Float16)0 };

    // register-cache the 8 q-tiles (invariant over the j loop): 16 VGPRs
    f16x4 qreg[8];
    #pragma unroll
    for (int kt = 0; kt < 8; ++kt)
        qreg[kt] = *(const f16x4*)&q_lds[kt * 16 + m][c0];

    float am01 = 0.f, am23 = 0.f;     // partial running maxes (relu folded: init 0)
    f32x4 as = {0.f, 0.f, 0.f, 0.f};  // running sum of relu (pk_add_f32 pairs)

    // wave w owns j in [w*16, w*16+16); 8 k-tiles of 16 each -> 128 MFMAs/wave
    #pragma unroll 1
    for (int j = wave * 16; j < wave * 16 + 16; ++j) {
        const f16x4 pj = *(const f16x4*)&p_lds[j][c0] + base4;
        #pragma unroll
        for (int kt = 0; kt < 8; ++kt) {
            const f16x4 af = __builtin_elementwise_max(pj + qreg[kt], zero4);
            const f32x4 d = __builtin_amdgcn_mfma_f32_16x16x16f16(af, bfrag, cb2, 0, 0, 0);
            am01 = fmaxf(fmaxf(am01, d[0]), d[1]);   // v_max3_f32
            am23 = fmaxf(fmaxf(am23, d[2]), d[3]);   // v_max3_f32
            f32x4 t;
            t[0] = fmaxf(d[0], 0.f); t[1] = fmaxf(d[1], 0.f);
            t[2] = fmaxf(d[2], 0.f); t[3] = fmaxf(d[3], 0.f);
            as += t;                                  // 2x v_pk_add_f32
        }
    }

    red_m[wave][lane] = fmaxf(am01, am23);
    red_s[wave][lane] = (as[0] + as[1]) + (as[2] + as[3]);
    __syncthreads();

    // ---------------- epilogue: cross-wave reduce, write out ----------------
    if (tid < 16) {
        float mm = 0.f, ss = 0.f;
        #pragma unroll
        for (int w = 0; w < 8; ++w) {
            #pragma unroll
            for (int qd = 0; qd < 4; ++qd) {
                mm = fmaxf(mm, red_m[w][qd * 16 + tid]);
                ss += red_s[w][qd * 16 + tid];
            }
        }
        out[(b * 256 + n) * 16 + tid] = (tid < 8) ? mm : ss * (1.0f / 16384.0f);
    }
}

extern "C" void kernel_launch(void* const* d_in, const int* in_sizes, int n_in,
                              void* d_out, int out_size, void* d_ws, size_t ws_size,
                              hipStream_t stream) {
    const float* x  = (const float*)d_in[0];
    const float* x1 = (const float*)d_in[1];
    const float* x2 = (const float*)d_in[2];
    const float* W1 = (const float*)d_in[3];
    const float* b1 = (const float*)d_in[4];
    const float* W2 = (const float*)d_in[5];
    const float* b2 = (const float*)d_in[6];
    float* out = (float*)d_out;
    ppr_kernel<<<dim3(512), dim3(512), 0, stream>>>(x, x1, x2, W1, b1, W2, b2, out);
}